// Round 3
// baseline (234.201 us; speedup 1.0000x reference)
//
#include <hip/hip_runtime.h>

// FourierMixer: ifft2(fft2(x)) on real x == identity (absmax 0.016 vs thr
// 0.108, verified). Pure HBM-bound copy: 128 MiB in + 128 MiB out.
//
// History:
//  R0-R2: grid-stride loop latency-bound; 4x 32MiB-strided nontemporal
//         float4 kernel -> 230.6 us total (fills ~160 us of that).
//  R3:    block-contiguous 32 KiB tiles, 4096 blocks x 8 float4/thr ->
//         217.4 us (kernel ~57 us = 4.7 TB/s; ceiling 6.3 TB/s = ~43 us).
//  R4:    theory = block-turnover overhead: 4096 short-lived blocks = two
//         residency generations, 32 KiB work each. Fix: 2048 blocks = ONE
//         full residency generation (8 blocks/CU x 256 CU, zero turnover),
//         64 KiB contiguous tile per block, 16 float4/thread in two 8-deep
//         load batches (8 outstanding loads, VGPR <= 64 so occupancy holds
//         at 8 waves/SIMD via __launch_bounds__(256, 8)).
//  R5:    R4 bench failed on container infra (no counters) — resubmitting
//         the identical kernel for a clean measurement.
//
// N = 33,554,432 floats = 8,388,608 float4 = 2048 blocks * 256 thr * 16.

typedef float v4f __attribute__((ext_vector_type(4)));

__global__ __launch_bounds__(256, 8) void fourier_mixer_copy(
    const v4f* __restrict__ in, v4f* __restrict__ out) {
  // Block b owns float4 range [b*4096, (b+1)*4096)  (= 64 KiB contiguous).
  const unsigned base = blockIdx.x * 4096u + threadIdx.x;
#pragma unroll
  for (unsigned i = 0; i < 2u; ++i) {
    const unsigned b = base + i * 2048u;
    v4f r[8];
#pragma unroll
    for (unsigned k = 0; k < 8u; ++k)
      r[k] = __builtin_nontemporal_load(&in[b + k * 256u]);
#pragma unroll
    for (unsigned k = 0; k < 8u; ++k)
      __builtin_nontemporal_store(r[k], &out[b + k * 256u]);
  }
}

extern "C" void kernel_launch(void* const* d_in, const int* in_sizes, int n_in,
                              void* d_out, int out_size, void* d_ws, size_t ws_size,
                              hipStream_t stream) {
  const v4f* x = (const v4f*)d_in[0];
  v4f* y = (v4f*)d_out;
  // 8,388,608 float4s exactly = 2048 blocks * 256 threads * 16 per thread
  fourier_mixer_copy<<<2048, 256, 0, stream>>>(x, y);
}

// Round 4
// 226.885 us; speedup vs baseline: 1.0322x; 1.0322x over previous
//
#include <hip/hip_runtime.h>

// FourierMixer: ifft2(fft2(x)) on real x == identity (absmax 0.016 vs thr
// 0.108, verified). Pure HBM-bound copy: 128 MiB in + 128 MiB out.
//
// History:
//  R0-R2: grid-stride loop latency-bound; strided nontemporal float4
//         kernel -> 230.6 us total (re-poison fills ~160 us of that).
//  R3:    block-contiguous 32 KiB tiles, 4096 blocks x 8 float4/thr ->
//         217.4 us (kernel ~57 us inferred = 4.7 TB/s; ceiling ~43 us).
//  R4/R5: 2048 blocks x 64 KiB tiles ("one residency generation") ->
//         234.2 us on a ~3.5% slower trace; corrected still ~+9 us vs R3.
//         Theory REFUTED: zero surplus blocks = no tail work-stealing;
//         deeper batches serialize. Block turnover was not the limiter.
//  R6:    this is a pure 128 MiB D2D memcpy — hand the copy to the
//         driver's tuned blit path via hipMemcpyAsync (sanctioned in
//         kernel_launch, graph-capturable). Same path quality as the
//         6.7 TB/s fillBuffer visible on every trace. If this matches R3
//         instead of beating it, ~217 us is the floor (fills are fixed
//         overhead) and we declare roofline.

extern "C" void kernel_launch(void* const* d_in, const int* in_sizes, int n_in,
                              void* d_out, int out_size, void* d_ws, size_t ws_size,
                              hipStream_t stream) {
  // 8 * 4096 * 1024 floats * 4 B = 134,217,728 bytes
  hipMemcpyAsync(d_out, d_in[0], 134217728u, hipMemcpyDeviceToDevice, stream);
}

// Round 5
// 224.956 us; speedup vs baseline: 1.0411x; 1.0086x over previous
//
#include <hip/hip_runtime.h>

// FourierMixer: ifft2(fft2(x)) on real x == identity (absmax 0.016 vs thr
// 0.108, verified). Pure HBM-bound copy: 128 MiB in + 128 MiB out.
//
// History (kernel-only times; 2 re-poison fills ~160 us are fixed):
//  R0-R2: strided nontemporal float4 -> ~71 us (3.7 TB/s), latency/thrash.
//  R3:    block-contiguous 32 KiB tiles, 4096 blk x 8 float4/thr, nt both
//         -> ~57 us (4.7 TB/s). BEST total: 217.4 us.
//  R4/R5: 2048 blk x 64 KiB "one generation" -> ~66 us. REFUTED (no tail
//         slack, deeper serialization).
//  R6:    hipMemcpyAsync blit -> ~66 us (4.1 TB/s). REFUTED (blit path is
//         not the tuned fillBuffer path).
//  R7:    A/B on cache policy ONLY vs R3: drop ALL nontemporal hints.
//         m13's 6.29 TB/s copy and the 6.7 TB/s fillBuffer both run
//         default policy; nt on load+store may forfeit TCC/IC buffering.
//         Geometry identical to R3. Predict kernel ~57 -> ~45-48 us.
//         If neutral/worse: declare roofline at ~217 us.
//
// N = 33,554,432 floats = 8,388,608 float4 = 4096 blocks * 256 thr * 8.

typedef float v4f __attribute__((ext_vector_type(4)));

__global__ __launch_bounds__(256) void fourier_mixer_copy(
    const v4f* __restrict__ in, v4f* __restrict__ out) {
  // Block b covers float4 indices [b*2048, (b+1)*2048)  (32 KiB tile).
  const unsigned base = blockIdx.x * 2048u + threadIdx.x;
  // 8 independent fully-coalesced 16B loads, default cache policy,
  // then 8 mirrored stores.
  v4f r0 = in[base + 0u * 256u];
  v4f r1 = in[base + 1u * 256u];
  v4f r2 = in[base + 2u * 256u];
  v4f r3 = in[base + 3u * 256u];
  v4f r4 = in[base + 4u * 256u];
  v4f r5 = in[base + 5u * 256u];
  v4f r6 = in[base + 6u * 256u];
  v4f r7 = in[base + 7u * 256u];
  out[base + 0u * 256u] = r0;
  out[base + 1u * 256u] = r1;
  out[base + 2u * 256u] = r2;
  out[base + 3u * 256u] = r3;
  out[base + 4u * 256u] = r4;
  out[base + 5u * 256u] = r5;
  out[base + 6u * 256u] = r6;
  out[base + 7u * 256u] = r7;
}

extern "C" void kernel_launch(void* const* d_in, const int* in_sizes, int n_in,
                              void* d_out, int out_size, void* d_ws, size_t ws_size,
                              hipStream_t stream) {
  const v4f* x = (const v4f*)d_in[0];
  v4f* y = (v4f*)d_out;
  // 8,388,608 float4s exactly = 4096 blocks * 256 threads * 8 per thread
  fourier_mixer_copy<<<4096, 256, 0, stream>>>(x, y);
}

// Round 6
// 218.509 us; speedup vs baseline: 1.0718x; 1.0295x over previous
//
#include <hip/hip_runtime.h>

// FourierMixer: ifft2(fft2(x)) on real x == identity (absmax 0.016 vs thr
// 0.108, verified). Pure HBM-bound copy: 128 MiB in + 128 MiB out.
//
// History (kernel-only times; 2 re-poison fills ~160 us are fixed):
//  R0-R2: strided nontemporal float4 -> ~70 us (3.8 TB/s).
//  R3:    block-contiguous 32 KiB tiles, 4096 blk x 256 thr x 8 float4,
//         nt load+store -> ~57 us (4.7 TB/s). BEST total: 217.4 us.
//  R4/R5: 2048 blk x 16 float4 -> ~66 us. REFUTED (tail imbalance).
//  R6:    hipMemcpyAsync blit -> ~66 us. REFUTED (not the tuned path).
//  R7:    default cache policy A/B -> ~65 us. nt is BETTER; keep it.
//  R8:    per-WAVE contiguous streams. In R3 a wave's 8 line-loads were
//         4 KiB-strided (fixed channel-step pattern, poor row locality).
//         Re-index so each wave owns a sequential 8 KiB stretch:
//         addr = blockBase + wave*512 + k*64 + lane (float4 units).
//         Coalescing per instruction unchanged (1 KiB/line). Predict
//         kernel ~57 -> ~45-50 us; if neutral, declare roofline ~217.
//
// N = 33,554,432 floats = 8,388,608 float4 = 4096 blocks * 256 thr * 8.

typedef float v4f __attribute__((ext_vector_type(4)));

__global__ __launch_bounds__(256) void fourier_mixer_copy(
    const v4f* __restrict__ in, v4f* __restrict__ out) {
  // Block b covers float4 indices [b*2048, (b+1)*2048)  (32 KiB tile).
  // Wave w (of 4) owns the sequential stretch [b*2048 + w*512, +512).
  const unsigned wave = threadIdx.x >> 6;   // 0..3
  const unsigned lane = threadIdx.x & 63u;  // 0..63
  const unsigned base = blockIdx.x * 2048u + wave * 512u + lane;
  // 8 sequential 1 KiB line-loads per wave (stride 64 float4 = 1 KiB),
  // 8-deep in flight, then mirrored nontemporal stores.
  v4f r0 = __builtin_nontemporal_load(&in[base + 0u * 64u]);
  v4f r1 = __builtin_nontemporal_load(&in[base + 1u * 64u]);
  v4f r2 = __builtin_nontemporal_load(&in[base + 2u * 64u]);
  v4f r3 = __builtin_nontemporal_load(&in[base + 3u * 64u]);
  v4f r4 = __builtin_nontemporal_load(&in[base + 4u * 64u]);
  v4f r5 = __builtin_nontemporal_load(&in[base + 5u * 64u]);
  v4f r6 = __builtin_nontemporal_load(&in[base + 6u * 64u]);
  v4f r7 = __builtin_nontemporal_load(&in[base + 7u * 64u]);
  __builtin_nontemporal_store(r0, &out[base + 0u * 64u]);
  __builtin_nontemporal_store(r1, &out[base + 1u * 64u]);
  __builtin_nontemporal_store(r2, &out[base + 2u * 64u]);
  __builtin_nontemporal_store(r3, &out[base + 3u * 64u]);
  __builtin_nontemporal_store(r4, &out[base + 4u * 64u]);
  __builtin_nontemporal_store(r5, &out[base + 5u * 64u]);
  __builtin_nontemporal_store(r6, &out[base + 6u * 64u]);
  __builtin_nontemporal_store(r7, &out[base + 7u * 64u]);
}

extern "C" void kernel_launch(void* const* d_in, const int* in_sizes, int n_in,
                              void* d_out, int out_size, void* d_ws, size_t ws_size,
                              hipStream_t stream) {
  const v4f* x = (const v4f*)d_in[0];
  v4f* y = (v4f*)d_out;
  // 8,388,608 float4s exactly = 4096 blocks * 256 threads * 8 per thread
  fourier_mixer_copy<<<4096, 256, 0, stream>>>(x, y);
}